// Round 4
// baseline (188.153 us; speedup 1.0000x reference)
//
#include <hip/hip_runtime.h>
#include <stdint.h>

// PRNG layout: partitionable counter-mode, bits = y0 ^ y1 (verified round 1)
// Round 4: k_dot decision batching. Round-3 counters: k_dot 41.5us,
// VALUBusy 49% => ~1.5k VALU cyc/wave-token, dominated by the exec-masked
// (lane<4) gumbel section (2 software fp64 logs) issued once PER WAVE.
// Now 512-thread blocks (8 tokens): per-wave fp64 dot (math unchanged),
// (d0,d1) -> LDS, wave 0 computes all 8 decisions with 32 active lanes
// (8x fewer gumbel issues per block), ballot-combine, keep -> LDS+mask.

#define NB 8
#define NT 4096
#define ND 512
#define NH 512
#define NTOK (NB * NT)

typedef __attribute__((ext_vector_type(8))) short short8;
typedef __attribute__((ext_vector_type(4))) float f32x4;

// ---- workspace layout (bytes) ----
#define WS_WEX   0          // 512*2 f64   : W_embed @ Wx
#define WS_PEX   8192       // 4096*2 f64  : (b_embed + pe[t]) @ Wx
#define WS_VWV   73728      // 2*8*2 f64   : v_i @ Wv
#define WS_LENS  76048      // 8 i32
#define WS_WT    76096      // 512*512 u16 : bf16 W_embed transposed [n][k]
#define WS_MASK  731456     // 32768 i32   : mask (k_dot) -> order (k_scan, in-place)
#define WS_ABF16 1310720    // 32768*512 u16 : bf16 data (selected rows only)

__device__ inline void threefry2x32(uint32_t k0, uint32_t k1, uint32_t x0, uint32_t x1,
                                    uint32_t& y0, uint32_t& y1) {
  uint32_t ks2 = k0 ^ k1 ^ 0x1BD11BDAu;
  x0 += k0; x1 += k1;
#define TFR(r) { x0 += x1; x1 = (x1 << (r)) | (x1 >> (32 - (r))); x1 ^= x0; }
  TFR(13) TFR(15) TFR(26) TFR(6)   x0 += k1;  x1 += ks2 + 1u;
  TFR(17) TFR(29) TFR(16) TFR(24)  x0 += ks2; x1 += k0 + 2u;
  TFR(13) TFR(15) TFR(26) TFR(6)   x0 += k0;  x1 += k1 + 3u;
  TFR(17) TFR(29) TFR(16) TFR(24)  x0 += k1;  x1 += ks2 + 4u;
  TFR(13) TFR(15) TFR(26) TFR(6)   x0 += ks2; x1 += k0 + 5u;
#undef TFR
  y0 = x0; y1 = x1;
}

__device__ inline uint32_t rb_bits(uint32_t k0, uint32_t k1, uint32_t idx) {
  uint32_t y0, y1;
  threefry2x32(k0, k1, 0u, idx, y0, y1);
  return y0 ^ y1;
}

__device__ inline double gumbel_from_bits(uint32_t bits) {
  uint32_t m = bits >> 9;
  float u = m ? (float)m * 1.1920928955078125e-07f : 1.17549435082228751e-38f;
  double lu = log((double)u);
  return -log(-lu);
}

__device__ inline uint16_t f2bf(float f) {
  union { float f; uint32_t u; } v; v.f = f;
  uint32_t u = v.u;
  return (uint16_t)((u + 0x7FFFu + ((u >> 16) & 1u)) >> 16);
}

__device__ inline double wredd(double v) {
#pragma unroll
  for (int o = 32; o > 0; o >>= 1) v += __shfl_xor(v, o, 64);
  return v;
}

// fast fp64 sincos for x in [0, ~4200): Cody-Waite + fdlibm polys, err ~1e-16
__device__ inline void fsincos(double x, double& sv, double& cv) {
  const double invpio2 = 6.36619772367581382433e-01;
  const double pio2_1  = 1.57079632673412561417e+00;
  const double pio2_1t = 6.07710050650619224932e-11;
  double fn = floor(x * invpio2 + 0.5);
  int n = (int)fn;
  double r = x - fn * pio2_1;
  r = r - fn * pio2_1t;
  double z = r * r;
  const double S1 = -1.66666666666666324348e-01, S2 = 8.33333333332248946124e-03,
               S3 = -1.98412698298579493134e-04, S4 = 2.75573137070700676789e-06,
               S5 = -2.50507602534068634195e-08, S6 = 1.58969099521155010221e-10;
  const double C1 = 4.16666666666666019037e-02, C2 = -1.38888888888741095749e-03,
               C3 = 2.48015872894767294178e-05, C4 = -2.75573143513906633035e-07,
               C5 = 2.08757232129817482790e-09, C6 = -1.13596475577881948265e-11;
  double ss = r + r * z * (S1 + z * (S2 + z * (S3 + z * (S4 + z * (S5 + z * S6)))));
  double cc = 1.0 + z * (-0.5 + z * (C1 + z * (C2 + z * (C3 + z * (C4 + z * (C5 + z * C6))))));
  int q = n & 3;
  sv = (q == 0) ? ss : (q == 1) ? cc : (q == 2) ? -ss : -cc;
  cv = (q == 0) ? cc : (q == 1) ? -ss : (q == 2) ? -cc : ss;
}

__device__ inline void gld_lds16(const void* g, void* l) {
  __builtin_amdgcn_global_load_lds(
      (const __attribute__((address_space(1))) void*)g,
      (__attribute__((address_space(3))) void*)l, 16, 0, 0);
}

// ---- k_prep: fp64 reduced operands + bf16 W^T (decision math UNCHANGED) ----
__global__ __launch_bounds__(64) void k_prep(
    const float* __restrict__ v0, const float* __restrict__ v1,
    const float* __restrict__ W, const float* __restrict__ be,
    const float* __restrict__ Wx, const float* __restrict__ Wv,
    char* __restrict__ ws) {
  double* Wex = (double*)(ws + WS_WEX);
  double* pex = (double*)(ws + WS_PEX);
  double* vWv = (double*)(ws + WS_VWV);
  uint16_t* Wt = (uint16_t*)(ws + WS_WT);
  __shared__ double divs[256];
  int blk = blockIdx.x;
  int lane = threadIdx.x;

  if (blk < 512) {
    int d = blk;
    double a0 = 0.0, a1 = 0.0;
    for (int it = 0; it < 8; ++it) {
      int h = it * 64 + lane;
      double w = (double)W[d * 512 + h];
      a0 += w * (double)Wx[2 * h];
      a1 += w * (double)Wx[2 * h + 1];
    }
    a0 = wredd(a0); a1 = wredd(a1);
    if (lane == 0) { Wex[2 * d] = a0; Wex[2 * d + 1] = a1; }
  } else if (blk < 4608) {
    const double c2 = -2.0 * 9.210340371976184 / 512.0;
    for (int it = 0; it < 4; ++it) {
      int f = it * 64 + lane;
      divs[f] = exp((double)f * c2);
    }
    __syncthreads();
    int t = blk - 512;
    double td = (double)t;
    double a0 = 0.0, a1 = 0.0;
    for (int it = 0; it < 8; ++it) {
      int h = it * 64 + lane;
      double dv = divs[h >> 1];
      double sv, cv;
      fsincos(td * dv, sv, cv);
      double pe = (h & 1) ? cv : sv;
      double pb = pe + (double)be[h];
      a0 += pb * (double)Wx[2 * h];
      a1 += pb * (double)Wx[2 * h + 1];
    }
    a0 = wredd(a0); a1 = wredd(a1);
    if (lane == 0) { pex[2 * t] = a0; pex[2 * t + 1] = a1; }
  } else if (blk < 4624) {
    int q = blk - 4608;
    int i = q >> 3, b = q & 7;
    const float* v = i ? v1 : v0;
    double a0 = 0.0, a1 = 0.0;
    for (int it = 0; it < 8; ++it) {
      int d = it * 64 + lane;
      double x = (double)v[b * 512 + d];
      a0 += x * (double)Wv[2 * d];
      a1 += x * (double)Wv[2 * d + 1];
    }
    a0 = wredd(a0); a1 = wredd(a1);
    if (lane == 0) { vWv[(i * 8 + b) * 2] = a0; vWv[(i * 8 + b) * 2 + 1] = a1; }
  } else {
    int kk = blk - 4624;
    for (int it = 0; it < 8; ++it) {
      int n = it * 64 + lane;
      Wt[(size_t)n * 512 + kk] = f2bf(W[kk * 512 + n]);
    }
  }
}

// ---- k_dot v2: per-wave fp64 dot; block-batched gumbel decision on wave 0 ----
__global__ __launch_bounds__(512) void k_dot(
    const float* __restrict__ data, const float* __restrict__ bfp,
    const char* __restrict__ wsc, int* __restrict__ mask,
    uint16_t* __restrict__ Abf) {
  const double* Wex = (const double*)(wsc + WS_WEX);
  const double* pex = (const double*)(wsc + WS_PEX);
  const double* vWv = (const double*)(wsc + WS_VWV);

  int wid = threadIdx.x >> 6;     // 0..7: token within block
  int lane = threadIdx.x & 63;
  int k0 = blockIdx.x * 8;
  int k = k0 + wid;

  const float4* dp = (const float4*)(data + (size_t)k * 512 + lane * 8);
  float4 f0 = dp[0], f1 = dp[1];
  float xv[8] = {f0.x, f0.y, f0.z, f0.w, f1.x, f1.y, f1.z, f1.w};

  const double* wx = Wex + lane * 16;
  double d0 = 0.0, d1 = 0.0;
#pragma unroll
  for (int u = 0; u < 8; ++u) {
    double x = (double)xv[u];
    d0 += x * wx[2 * u];
    d1 += x * wx[2 * u + 1];
  }
  d0 = wredd(d0); d1 = wredd(d1);

  __shared__ double dsh[8][2];
  __shared__ int keep_sh[8];
  if (lane == 0) { dsh[wid][0] = d0; dsh[wid][1] = d1; }
  __syncthreads();

  // decision for all 8 tokens on wave 0: lane = 4*tt + 2*i + j (32 active)
  if (wid == 0) {
    int dec = 0;
    if (lane < 32) {
      int tt = lane >> 2, i = (lane >> 1) & 1, j = lane & 1;
      int kk = k0 + tt;
      int bb = kk >> 12, ttok = kk & 4095;
      uint32_t key0, key1;
      threefry2x32(0u, 42u, 0u, (uint32_t)i, key0, key1);
      double dj = dsh[tt][j];
      double lj = 8.0 * (dj + pex[ttok * 2 + j]) + (double)bfp[j];
      double z = lj + vWv[(i * 8 + bb) * 2 + j]
                   + gumbel_from_bits(rb_bits(key0, key1, (uint32_t)(2 * kk + j)));
      double zo = __shfl_xor(z, 1, 64);
      dec = (z >= zo) ? 1 : 0;  // meaningful at j==0 lanes (class-0 wins ties)
    }
    unsigned long long bal = __ballot(dec);
    if (lane < 8) {
      int keep = (int)((bal >> (lane * 4)) & (bal >> (lane * 4 + 2)) & 1ULL);
      keep_sh[lane] = keep;
      mask[k0 + lane] = keep;
    }
  }
  __syncthreads();

  // bf16 side-write only for kept tokens (wave-uniform branch)
  if (keep_sh[wid]) {
    short8 o;
#pragma unroll
    for (int u = 0; u < 8; ++u) o[u] = (short)f2bf(xv[u]);
    *(short8*)(Abf + (size_t)k * 512 + lane * 8) = o;
  }
}

// ---- k_scan: mask -> order (packed pos -> token, in-place over mask) + lens ----
__global__ __launch_bounds__(1024) void k_scan(
    int* __restrict__ morder, int* __restrict__ lens) {
  __shared__ int wsum[16];
  int b = blockIdx.x, tid = threadIdx.x;
  int wid = tid >> 6, lane = tid & 63;
  int t0 = tid * 4;
  int4 mv = *(const int4*)(morder + b * 4096 + t0);
  int m[4] = {mv.x, mv.y, mv.z, mv.w};
  int p = m[0] + m[1] + m[2] + m[3];

  int s = p;
#pragma unroll
  for (int off = 1; off < 64; off <<= 1) {
    int v = __shfl_up(s, off, 64);
    if (lane >= off) s += v;
  }
  if (lane == 63) wsum[wid] = s;
  __syncthreads();
  if (wid == 0) {
    int w = (lane < 16) ? wsum[lane] : 0;
#pragma unroll
    for (int off = 1; off < 16; off <<= 1) {
      int v = __shfl_up(w, off, 64);
      if (lane >= off) w += v;
    }
    if (lane < 16) wsum[lane] = w;
  }
  __syncthreads();
  int run = ((wid > 0) ? wsum[wid - 1] : 0) + s - p;
  int base = b * 4096;
  if (m[0]) morder[base + run] = t0 + 0;
  run += m[0];
  if (m[1]) morder[base + run] = t0 + 1;
  run += m[1];
  if (m[2]) morder[base + run] = t0 + 2;
  run += m[2];
  if (m[3]) morder[base + run] = t0 + 3;
  if (tid == 1023) lens[b] = wsum[15];
}

// ---- k_zero: fill out rows j >= lens[b] with zeros ----
__global__ __launch_bounds__(256) void k_zero(
    const char* __restrict__ wsc, float* __restrict__ out) {
  const int* lens = (const int*)(wsc + WS_LENS);
  int b = blockIdx.y;
  int j = blockIdx.x * 4 + (threadIdx.x >> 6);
  if (j < lens[b]) return;
  int lane = threadIdx.x & 63;
  float4 z = {0.f, 0.f, 0.f, 0.f};
  float* op = out + ((size_t)(b * 4096 + j)) * 512 + lane * 8;
  *(float4*)op = z;
  *(float4*)(op + 4) = z;
}

// ---- k_gemm v8: packed-GLOBAL row mapping, per-row batch resolve ----
#define BM 128
#define BN 128
#define BK 32

__global__ __launch_bounds__(256) void k_gemm(
    const uint16_t* __restrict__ Abf, const float* __restrict__ be,
    const char* __restrict__ wsc, float* __restrict__ out) {
  const uint16_t* Wt = (const uint16_t*)(wsc + WS_WT);
  const int* order = (const int*)(wsc + WS_MASK);
  const int* lens = (const int*)(wsc + WS_LENS);

  // prefix over batches (uniform -> scalar regs)
  int cum[9];
  cum[0] = 0;
#pragma unroll
  for (int i = 0; i < 8; ++i) cum[i + 1] = cum[i] + lens[i];
  int S = cum[8];

  int bid = blockIdx.x;
  int nb = bid & 3;               // N-block (128 cols each)
  int G = (bid >> 2) * BM;        // packed-GLOBAL row base
  if (G >= S) return;             // contiguous working ids 0..~ceil(S/128)*4

  int tid = threadIdx.x;
  int wave = tid >> 6, lane = tid & 63;
  int wm = wave & 1, wn = wave >> 1;
  int quad = lane >> 4, l15 = lane & 15;
  int srow = lane >> 2;
  int scol = (lane & 3) * 8;

  __shared__ __align__(16) uint16_t As[BM * BK];
  __shared__ __align__(16) uint16_t Bs[BN * BK];

  f32x4 acc[4][4] = {};

  // per-lane gathered A rows: resolve packed-global -> (batch, in-batch pos)
  int lr = wave * 16 + srow;      // local row in [0,64)
  int pg0 = G + lr, pg1 = pg0 + 64;
  int b0 = 0, pin0 = pg0, b1 = 0, pin1 = pg1;
#pragma unroll
  for (int i = 1; i < 8; ++i) {
    if (pg0 >= cum[i]) { b0 = i; pin0 = pg0 - cum[i]; }
    if (pg1 >= cum[i]) { b1 = i; pin1 = pg1 - cum[i]; }
  }
  if (pg0 >= S) { b0 = 0; pin0 = 0; }  // clamp: reads a valid allocation
  if (pg1 >= S) { b1 = 0; pin1 = 0; }
  int t0r = order[(b0 << 12) + pin0];
  int t1r = order[(b1 << 12) + pin1];
  const uint16_t* a0p = Abf + (((size_t)(b0 << 12) + t0r) << 9) + scol;
  const uint16_t* a1p = Abf + (((size_t)(b1 << 12) + t1r) << 9) + scol;
  const uint16_t* gB = Wt + (size_t)(nb * BN) * 512;
  const uint16_t* b0p = gB + (size_t)lr * 512 + scol;
  const uint16_t* b1p = b0p + (size_t)64 * 512;

  uint16_t* lA = As + (size_t)(wave * 16) * BK;  // wave-uniform LDS base
  uint16_t* lB = Bs + (size_t)(wave * 16) * BK;

  for (int k0 = 0; k0 < 512; k0 += BK) {
    gld_lds16(a0p + k0, lA);
    gld_lds16(a1p + k0, lA + 64 * BK);
    gld_lds16(b0p + k0, lB);
    gld_lds16(b1p + k0, lB + 64 * BK);
    __syncthreads();

    short8 af[4], bfr[4];
#pragma unroll
    for (int mi = 0; mi < 4; ++mi)
      af[mi] = *(const short8*)&As[(wm * 64 + mi * 16 + l15) * BK + quad * 8];
#pragma unroll
    for (int ni = 0; ni < 4; ++ni)
      bfr[ni] = *(const short8*)&Bs[(wn * 64 + ni * 16 + l15) * BK + quad * 8];
#pragma unroll
    for (int mi = 0; mi < 4; ++mi)
#pragma unroll
      for (int ni = 0; ni < 4; ++ni)
        acc[mi][ni] = __builtin_amdgcn_mfma_f32_16x16x32_bf16(af[mi], bfr[ni], acc[mi][ni], 0, 0, 0);
    __syncthreads();
  }

  // per-row (token, out-row) into LDS (As/Bs dead after final barrier)
  int* ords = (int*)As;
  int* orows = (int*)Bs;
  if (tid < 128) {
    int pg = G + tid;
    int bb = 0, pp = pg;
#pragma unroll
    for (int i = 1; i < 8; ++i)
      if (pg >= cum[i]) { bb = i; pp = pg - cum[i]; }
    bool val = pg < S;
    ords[tid] = val ? order[(bb << 12) + pp] : 0;
    orows[tid] = val ? ((bb << 12) + pp) : -1;
  }
  __syncthreads();

  // contiguous epilogue: out[orow][n] = 8*(acc + be + pe(t,n))
  const float c1 = -0.01798894603951557739f;  // -ln(10000)/512
#pragma unroll
  for (int ni = 0; ni < 4; ++ni) {
    int n = nb * BN + wn * 64 + ni * 16 + l15;
    float dv = __expf((float)(n & ~1) * c1);
    float ben = be[n];
#pragma unroll
    for (int mi = 0; mi < 4; ++mi) {
#pragma unroll
      for (int r = 0; r < 4; ++r) {
        int lrow = wm * 64 + mi * 16 + quad * 4 + r;
        int oj = orows[lrow];
        if (oj >= 0) {
          int t = ords[lrow];
          float ph = (float)t * dv;
          float pe = (n & 1) ? __cosf(ph) : __sinf(ph);
          out[((size_t)oj) * 512 + n] = 8.0f * (acc[mi][ni][r] + ben + pe);
        }
      }
    }
  }
}

extern "C" void kernel_launch(void* const* d_in, const int* in_sizes, int n_in,
                              void* d_out, int out_size, void* d_ws, size_t ws_size,
                              hipStream_t stream) {
  const float* data = (const float*)d_in[0];
  const float* v0   = (const float*)d_in[1];
  const float* v1   = (const float*)d_in[2];
  const float* W    = (const float*)d_in[3];
  const float* be   = (const float*)d_in[4];
  const float* Wx   = (const float*)d_in[5];
  const float* Wv   = (const float*)d_in[6];
  const float* bfp  = (const float*)d_in[7];
  char* ws = (char*)d_ws;
  float* out = (float*)d_out;
  uint16_t* Abf = (uint16_t*)(ws + WS_ABF16);

  hipLaunchKernelGGL(k_prep, dim3(5136), dim3(64), 0, stream, v0, v1, W, be, Wx, Wv, ws);
  hipLaunchKernelGGL(k_dot, dim3(4096), dim3(512), 0, stream,
                     data, bfp, (const char*)ws, (int*)(ws + WS_MASK), Abf);
  hipLaunchKernelGGL(k_scan, dim3(8), dim3(1024), 0, stream,
                     (int*)(ws + WS_MASK), (int*)(ws + WS_LENS));
  hipLaunchKernelGGL(k_zero, dim3(1024, 8), dim3(256), 0, stream, (const char*)ws, out);
  hipLaunchKernelGGL(k_gemm, dim3(1024), dim3(256), 0, stream,
                     Abf, be, (const char*)ws, out);
}

// Round 6
// 171.580 us; speedup vs baseline: 1.0966x; 1.0966x over previous
//
#include <hip/hip_runtime.h>
#include <stdint.h>

// PRNG layout: partitionable counter-mode, bits = y0 ^ y1 (verified round 1)
// Round 6 (resubmit of round 5 — infra failure, no counters; precedent:
// round 2 infra failure, identical resubmit passed in round 3).
// k_dot Wex de-scatter. Round 3 vs 4 A/B: VALUBusy 49% -> 15% with dur FLAT
// at 41us => VALU was never the limit. Shared pattern: per-lane Wex slice at
// 128B lane stride = 64 cachelines per load instr, ~1k L1 transactions/wave
// => L1 transaction-rate bound (~55us/CU at 1/cyc). Fix: transpose lane
// mapping (lane l owns d-indices u*64+l): Wex becomes coalesced double2
// loads held in 32 VGPRs per wave (amortized over 4 tokens/wave); data 8
// coalesced dwords/token; bf16 write unconditional (decouples stores from
// the gumbel dep chain); no LDS, no barriers.

#define NB 8
#define NT 4096
#define ND 512
#define NH 512
#define NTOK (NB * NT)

typedef __attribute__((ext_vector_type(8))) short short8;
typedef __attribute__((ext_vector_type(4))) float f32x4;

// ---- workspace layout (bytes) ----
#define WS_WEX   0          // 512*2 f64   : W_embed @ Wx
#define WS_PEX   8192       // 4096*2 f64  : (b_embed + pe[t]) @ Wx
#define WS_VWV   73728      // 2*8*2 f64   : v_i @ Wv
#define WS_LENS  76048      // 8 i32
#define WS_WT    76096      // 512*512 u16 : bf16 W_embed transposed [n][k]
#define WS_MASK  731456     // 32768 i32   : mask (k_dot) -> order (k_scan, in-place)
#define WS_ABF16 1310720    // 32768*512 u16 : dense bf16 data

__device__ inline void threefry2x32(uint32_t k0, uint32_t k1, uint32_t x0, uint32_t x1,
                                    uint32_t& y0, uint32_t& y1) {
  uint32_t ks2 = k0 ^ k1 ^ 0x1BD11BDAu;
  x0 += k0; x1 += k1;
#define TFR(r) { x0 += x1; x1 = (x1 << (r)) | (x1 >> (32 - (r))); x1 ^= x0; }
  TFR(13) TFR(15) TFR(26) TFR(6)   x0 += k1;  x1 += ks2 + 1u;
  TFR(17) TFR(29) TFR(16) TFR(24)  x0 += ks2; x1 += k0 + 2u;
  TFR(13) TFR(15) TFR(26) TFR(6)   x0 += k0;  x1 += k1 + 3u;
  TFR(17) TFR(29) TFR(16) TFR(24)  x0 += k1;  x1 += ks2 + 4u;
  TFR(13) TFR(15) TFR(26) TFR(6)   x0 += ks2; x1 += k0 + 5u;
#undef TFR
  y0 = x0; y1 = x1;
}

__device__ inline uint32_t rb_bits(uint32_t k0, uint32_t k1, uint32_t idx) {
  uint32_t y0, y1;
  threefry2x32(k0, k1, 0u, idx, y0, y1);
  return y0 ^ y1;
}

__device__ inline double gumbel_from_bits(uint32_t bits) {
  uint32_t m = bits >> 9;
  float u = m ? (float)m * 1.1920928955078125e-07f : 1.17549435082228751e-38f;
  double lu = log((double)u);
  return -log(-lu);
}

__device__ inline uint16_t f2bf(float f) {
  union { float f; uint32_t u; } v; v.f = f;
  uint32_t u = v.u;
  return (uint16_t)((u + 0x7FFFu + ((u >> 16) & 1u)) >> 16);
}

__device__ inline double wredd(double v) {
#pragma unroll
  for (int o = 32; o > 0; o >>= 1) v += __shfl_xor(v, o, 64);
  return v;
}

// fast fp64 sincos for x in [0, ~4200): Cody-Waite + fdlibm polys, err ~1e-16
__device__ inline void fsincos(double x, double& sv, double& cv) {
  const double invpio2 = 6.36619772367581382433e-01;
  const double pio2_1  = 1.57079632673412561417e+00;
  const double pio2_1t = 6.07710050650619224932e-11;
  double fn = floor(x * invpio2 + 0.5);
  int n = (int)fn;
  double r = x - fn * pio2_1;
  r = r - fn * pio2_1t;
  double z = r * r;
  const double S1 = -1.66666666666666324348e-01, S2 = 8.33333333332248946124e-03,
               S3 = -1.98412698298579493134e-04, S4 = 2.75573137070700676789e-06,
               S5 = -2.50507602534068634195e-08, S6 = 1.58969099521155010221e-10;
  const double C1 = 4.16666666666666019037e-02, C2 = -1.38888888888741095749e-03,
               C3 = 2.48015872894767294178e-05, C4 = -2.75573143513906633035e-07,
               C5 = 2.08757232129817482790e-09, C6 = -1.13596475577881948265e-11;
  double ss = r + r * z * (S1 + z * (S2 + z * (S3 + z * (S4 + z * (S5 + z * S6)))));
  double cc = 1.0 + z * (-0.5 + z * (C1 + z * (C2 + z * (C3 + z * (C4 + z * (C5 + z * C6))))));
  int q = n & 3;
  sv = (q == 0) ? ss : (q == 1) ? cc : (q == 2) ? -ss : -cc;
  cv = (q == 0) ? cc : (q == 1) ? -ss : (q == 2) ? -cc : ss;
}

__device__ inline void gld_lds16(const void* g, void* l) {
  __builtin_amdgcn_global_load_lds(
      (const __attribute__((address_space(1))) void*)g,
      (__attribute__((address_space(3))) void*)l, 16, 0, 0);
}

// ---- k_prep: fp64 reduced operands + bf16 W^T (decision math UNCHANGED) ----
__global__ __launch_bounds__(64) void k_prep(
    const float* __restrict__ v0, const float* __restrict__ v1,
    const float* __restrict__ W, const float* __restrict__ be,
    const float* __restrict__ Wx, const float* __restrict__ Wv,
    char* __restrict__ ws) {
  double* Wex = (double*)(ws + WS_WEX);
  double* pex = (double*)(ws + WS_PEX);
  double* vWv = (double*)(ws + WS_VWV);
  uint16_t* Wt = (uint16_t*)(ws + WS_WT);
  __shared__ double divs[256];
  int blk = blockIdx.x;
  int lane = threadIdx.x;

  if (blk < 512) {
    int d = blk;
    double a0 = 0.0, a1 = 0.0;
    for (int it = 0; it < 8; ++it) {
      int h = it * 64 + lane;
      double w = (double)W[d * 512 + h];
      a0 += w * (double)Wx[2 * h];
      a1 += w * (double)Wx[2 * h + 1];
    }
    a0 = wredd(a0); a1 = wredd(a1);
    if (lane == 0) { Wex[2 * d] = a0; Wex[2 * d + 1] = a1; }
  } else if (blk < 4608) {
    const double c2 = -2.0 * 9.210340371976184 / 512.0;
    for (int it = 0; it < 4; ++it) {
      int f = it * 64 + lane;
      divs[f] = exp((double)f * c2);
    }
    __syncthreads();
    int t = blk - 512;
    double td = (double)t;
    double a0 = 0.0, a1 = 0.0;
    for (int it = 0; it < 8; ++it) {
      int h = it * 64 + lane;
      double dv = divs[h >> 1];
      double sv, cv;
      fsincos(td * dv, sv, cv);
      double pe = (h & 1) ? cv : sv;
      double pb = pe + (double)be[h];
      a0 += pb * (double)Wx[2 * h];
      a1 += pb * (double)Wx[2 * h + 1];
    }
    a0 = wredd(a0); a1 = wredd(a1);
    if (lane == 0) { pex[2 * t] = a0; pex[2 * t + 1] = a1; }
  } else if (blk < 4624) {
    int q = blk - 4608;
    int i = q >> 3, b = q & 7;
    const float* v = i ? v1 : v0;
    double a0 = 0.0, a1 = 0.0;
    for (int it = 0; it < 8; ++it) {
      int d = it * 64 + lane;
      double x = (double)v[b * 512 + d];
      a0 += x * (double)Wv[2 * d];
      a1 += x * (double)Wv[2 * d + 1];
    }
    a0 = wredd(a0); a1 = wredd(a1);
    if (lane == 0) { vWv[(i * 8 + b) * 2] = a0; vWv[(i * 8 + b) * 2 + 1] = a1; }
  } else {
    int kk = blk - 4624;
    for (int it = 0; it < 8; ++it) {
      int n = it * 64 + lane;
      Wt[(size_t)n * 512 + kk] = f2bf(W[kk * 512 + n]);
    }
  }
}

// ---- k_dot v3: coalesced transposed-lane dot; Wex in VGPRs; 4 tokens/wave ----
__global__ __launch_bounds__(256) void k_dot(
    const float* __restrict__ data, const float* __restrict__ bfp,
    const char* __restrict__ wsc, int* __restrict__ mask,
    uint16_t* __restrict__ Abf) {
  const double* Wex = (const double*)(wsc + WS_WEX);
  const double* pex = (const double*)(wsc + WS_PEX);
  const double* vWv = (const double*)(wsc + WS_VWV);

  int wid = threadIdx.x >> 6;
  int lane = threadIdx.x & 63;
  int kbase = (blockIdx.x * 4 + wid) * 4;   // 4 tokens per wave

  // Wex slice in regs: lane l holds w{0,1}[u] = Wex[2*(u*64+l)+{0,1}]
  // (coalesced double2: lane stride 16B) — loaded once, reused for 4 tokens
  double w0[8], w1[8];
#pragma unroll
  for (int u = 0; u < 8; ++u) {
    double2 wv = *(const double2*)(Wex + 2 * (u * 64 + lane));
    w0[u] = wv.x; w1[u] = wv.y;
  }

  double d0s[4], d1s[4];
#pragma unroll
  for (int tt = 0; tt < 4; ++tt) {
    int k = kbase + tt;
    const float* dpt = data + (size_t)k * 512 + lane;
    float x[8];
#pragma unroll
    for (int u = 0; u < 8; ++u) x[u] = dpt[u * 64];   // coalesced dwords

    // dense bf16 side-write, unconditional (decoupled from decision chain)
    uint16_t* ap = Abf + (size_t)k * 512 + lane;
#pragma unroll
    for (int u = 0; u < 8; ++u) ap[u * 64] = f2bf(x[u]);

    double d0 = 0.0, d1 = 0.0;
#pragma unroll
    for (int u = 0; u < 8; ++u) {
      double xd = (double)x[u];
      d0 += xd * w0[u];
      d1 += xd * w1[u];
    }
    d0s[tt] = wredd(d0);
    d1s[tt] = wredd(d1);
  }

  // batched decision: lanes 0-15, lane = 4*tt + 2*i + j
  int dec = 0;
  if (lane < 16) {
    int tt = lane >> 2, i = (lane >> 1) & 1, j = lane & 1;
    // cndmask select tree (compile-time reg indices; no scratch)
    double da = (tt & 2) ? ((tt & 1) ? d0s[3] : d0s[2])
                         : ((tt & 1) ? d0s[1] : d0s[0]);
    double db = (tt & 2) ? ((tt & 1) ? d1s[3] : d1s[2])
                         : ((tt & 1) ? d1s[1] : d1s[0]);
    double dj = j ? db : da;
    int kk = kbase + tt;
    int bb = kk >> 12, ttok = kk & 4095;
    uint32_t key0, key1;
    threefry2x32(0u, 42u, 0u, (uint32_t)i, key0, key1);
    double lj = 8.0 * (dj + pex[ttok * 2 + j]) + (double)bfp[j];
    double z = lj + vWv[(i * 8 + bb) * 2 + j]
                 + gumbel_from_bits(rb_bits(key0, key1, (uint32_t)(2 * kk + j)));
    double zo = __shfl_xor(z, 1, 64);
    dec = (z >= zo) ? 1 : 0;  // meaningful at j==0 lanes (class-0 wins ties)
  }
  unsigned long long bal = __ballot(dec);
  if (lane < 4)
    mask[kbase + lane] =
        (int)((bal >> (lane * 4)) & (bal >> (lane * 4 + 2)) & 1ULL);
}

// ---- k_scan: mask -> order (packed pos -> token, in-place over mask) + lens ----
__global__ __launch_bounds__(1024) void k_scan(
    int* __restrict__ morder, int* __restrict__ lens) {
  __shared__ int wsum[16];
  int b = blockIdx.x, tid = threadIdx.x;
  int wid = tid >> 6, lane = tid & 63;
  int t0 = tid * 4;
  int4 mv = *(const int4*)(morder + b * 4096 + t0);
  int m[4] = {mv.x, mv.y, mv.z, mv.w};
  int p = m[0] + m[1] + m[2] + m[3];

  int s = p;
#pragma unroll
  for (int off = 1; off < 64; off <<= 1) {
    int v = __shfl_up(s, off, 64);
    if (lane >= off) s += v;
  }
  if (lane == 63) wsum[wid] = s;
  __syncthreads();
  if (wid == 0) {
    int w = (lane < 16) ? wsum[lane] : 0;
#pragma unroll
    for (int off = 1; off < 16; off <<= 1) {
      int v = __shfl_up(w, off, 64);
      if (lane >= off) w += v;
    }
    if (lane < 16) wsum[lane] = w;
  }
  __syncthreads();
  int run = ((wid > 0) ? wsum[wid - 1] : 0) + s - p;
  int base = b * 4096;
  if (m[0]) morder[base + run] = t0 + 0;
  run += m[0];
  if (m[1]) morder[base + run] = t0 + 1;
  run += m[1];
  if (m[2]) morder[base + run] = t0 + 2;
  run += m[2];
  if (m[3]) morder[base + run] = t0 + 3;
  if (tid == 1023) lens[b] = wsum[15];
}

// ---- k_zero: fill out rows j >= lens[b] with zeros ----
__global__ __launch_bounds__(256) void k_zero(
    const char* __restrict__ wsc, float* __restrict__ out) {
  const int* lens = (const int*)(wsc + WS_LENS);
  int b = blockIdx.y;
  int j = blockIdx.x * 4 + (threadIdx.x >> 6);
  if (j < lens[b]) return;
  int lane = threadIdx.x & 63;
  float4 z = {0.f, 0.f, 0.f, 0.f};
  float* op = out + ((size_t)(b * 4096 + j)) * 512 + lane * 8;
  *(float4*)op = z;
  *(float4*)(op + 4) = z;
}

// ---- k_gemm v8: packed-GLOBAL row mapping, per-row batch resolve ----
#define BM 128
#define BN 128
#define BK 32

__global__ __launch_bounds__(256) void k_gemm(
    const uint16_t* __restrict__ Abf, const float* __restrict__ be,
    const char* __restrict__ wsc, float* __restrict__ out) {
  const uint16_t* Wt = (const uint16_t*)(wsc + WS_WT);
  const int* order = (const int*)(wsc + WS_MASK);
  const int* lens = (const int*)(wsc + WS_LENS);

  // prefix over batches (uniform -> scalar regs)
  int cum[9];
  cum[0] = 0;
#pragma unroll
  for (int i = 0; i < 8; ++i) cum[i + 1] = cum[i] + lens[i];
  int S = cum[8];

  int bid = blockIdx.x;
  int nb = bid & 3;               // N-block (128 cols each)
  int G = (bid >> 2) * BM;        // packed-GLOBAL row base
  if (G >= S) return;             // contiguous working ids 0..~ceil(S/128)*4

  int tid = threadIdx.x;
  int wave = tid >> 6, lane = tid & 63;
  int wm = wave & 1, wn = wave >> 1;
  int quad = lane >> 4, l15 = lane & 15;
  int srow = lane >> 2;
  int scol = (lane & 3) * 8;

  __shared__ __align__(16) uint16_t As[BM * BK];
  __shared__ __align__(16) uint16_t Bs[BN * BK];

  f32x4 acc[4][4] = {};

  // per-lane gathered A rows: resolve packed-global -> (batch, in-batch pos)
  int lr = wave * 16 + srow;      // local row in [0,64)
  int pg0 = G + lr, pg1 = pg0 + 64;
  int b0 = 0, pin0 = pg0, b1 = 0, pin1 = pg1;
#pragma unroll
  for (int i = 1; i < 8; ++i) {
    if (pg0 >= cum[i]) { b0 = i; pin0 = pg0 - cum[i]; }
    if (pg1 >= cum[i]) { b1 = i; pin1 = pg1 - cum[i]; }
  }
  if (pg0 >= S) { b0 = 0; pin0 = 0; }  // clamp: reads a valid kept row
  if (pg1 >= S) { b1 = 0; pin1 = 0; }
  int t0r = order[(b0 << 12) + pin0];
  int t1r = order[(b1 << 12) + pin1];
  const uint16_t* a0p = Abf + (((size_t)(b0 << 12) + t0r) << 9) + scol;
  const uint16_t* a1p = Abf + (((size_t)(b1 << 12) + t1r) << 9) + scol;
  const uint16_t* gB = Wt + (size_t)(nb * BN) * 512;
  const uint16_t* b0p = gB + (size_t)lr * 512 + scol;
  const uint16_t* b1p = b0p + (size_t)64 * 512;

  uint16_t* lA = As + (size_t)(wave * 16) * BK;  // wave-uniform LDS base
  uint16_t* lB = Bs + (size_t)(wave * 16) * BK;

  for (int k0 = 0; k0 < 512; k0 += BK) {
    gld_lds16(a0p + k0, lA);
    gld_lds16(a1p + k0, lA + 64 * BK);
    gld_lds16(b0p + k0, lB);
    gld_lds16(b1p + k0, lB + 64 * BK);
    __syncthreads();

    short8 af[4], bfr[4];
#pragma unroll
    for (int mi = 0; mi < 4; ++mi)
      af[mi] = *(const short8*)&As[(wm * 64 + mi * 16 + l15) * BK + quad * 8];
#pragma unroll
    for (int ni = 0; ni < 4; ++ni)
      bfr[ni] = *(const short8*)&Bs[(wn * 64 + ni * 16 + l15) * BK + quad * 8];
#pragma unroll
    for (int mi = 0; mi < 4; ++mi)
#pragma unroll
      for (int ni = 0; ni < 4; ++ni)
        acc[mi][ni] = __builtin_amdgcn_mfma_f32_16x16x32_bf16(af[mi], bfr[ni], acc[mi][ni], 0, 0, 0);
    __syncthreads();
  }

  // per-row (token, out-row) into LDS (As/Bs dead after final barrier)
  int* ords = (int*)As;
  int* orows = (int*)Bs;
  if (tid < 128) {
    int pg = G + tid;
    int bb = 0, pp = pg;
#pragma unroll
    for (int i = 1; i < 8; ++i)
      if (pg >= cum[i]) { bb = i; pp = pg - cum[i]; }
    bool val = pg < S;
    ords[tid] = val ? order[(bb << 12) + pp] : 0;
    orows[tid] = val ? ((bb << 12) + pp) : -1;
  }
  __syncthreads();

  // contiguous epilogue: out[orow][n] = 8*(acc + be + pe(t,n))
  const float c1 = -0.01798894603951557739f;  // -ln(10000)/512
#pragma unroll
  for (int ni = 0; ni < 4; ++ni) {
    int n = nb * BN + wn * 64 + ni * 16 + l15;
    float dv = __expf((float)(n & ~1) * c1);
    float ben = be[n];
#pragma unroll
    for (int mi = 0; mi < 4; ++mi) {
#pragma unroll
      for (int r = 0; r < 4; ++r) {
        int lrow = wm * 64 + mi * 16 + quad * 4 + r;
        int oj = orows[lrow];
        if (oj >= 0) {
          int t = ords[lrow];
          float ph = (float)t * dv;
          float pe = (n & 1) ? __cosf(ph) : __sinf(ph);
          out[((size_t)oj) * 512 + n] = 8.0f * (acc[mi][ni][r] + ben + pe);
        }
      }
    }
  }
}

extern "C" void kernel_launch(void* const* d_in, const int* in_sizes, int n_in,
                              void* d_out, int out_size, void* d_ws, size_t ws_size,
                              hipStream_t stream) {
  const float* data = (const float*)d_in[0];
  const float* v0   = (const float*)d_in[1];
  const float* v1   = (const float*)d_in[2];
  const float* W    = (const float*)d_in[3];
  const float* be   = (const float*)d_in[4];
  const float* Wx   = (const float*)d_in[5];
  const float* Wv   = (const float*)d_in[6];
  const float* bfp  = (const float*)d_in[7];
  char* ws = (char*)d_ws;
  float* out = (float*)d_out;
  uint16_t* Abf = (uint16_t*)(ws + WS_ABF16);

  hipLaunchKernelGGL(k_prep, dim3(5136), dim3(64), 0, stream, v0, v1, W, be, Wx, Wv, ws);
  hipLaunchKernelGGL(k_dot, dim3(2048), dim3(256), 0, stream,
                     data, bfp, (const char*)ws, (int*)(ws + WS_MASK), Abf);
  hipLaunchKernelGGL(k_scan, dim3(8), dim3(1024), 0, stream,
                     (int*)(ws + WS_MASK), (int*)(ws + WS_LENS));
  hipLaunchKernelGGL(k_zero, dim3(1024, 8), dim3(256), 0, stream, (const char*)ws, out);
  hipLaunchKernelGGL(k_gemm, dim3(1024), dim3(256), 0, stream,
                     Abf, be, (const char*)ws, out);
}

// Round 7
// 164.869 us; speedup vs baseline: 1.1412x; 1.0407x over previous
//
#include <hip/hip_runtime.h>
#include <stdint.h>

// PRNG layout: partitionable counter-mode, bits = y0 ^ y1 (verified round 1)
// Round 7: (a) k_gemm BM 128->64: round-6 state has ~492 working blocks =
// 2 blocks/CU = 2 waves/SIMD -> barrier-drain stall bare. 984 blocks @ 64x128
// gives ~3.8 blocks/CU (~15 waves/CU) for implicit wave-overlap; total
// A-traffic unchanged, B re-fetch from L2-resident 524KB Wt. (b) k_dot:
// kept-rows-only bf16 store (x held in regs across the decision; coalesced),
// -17MB HBM writes. Decision math unchanged in both.

#define NB 8
#define NT 4096
#define ND 512
#define NH 512
#define NTOK (NB * NT)

typedef __attribute__((ext_vector_type(8))) short short8;
typedef __attribute__((ext_vector_type(4))) float f32x4;

// ---- workspace layout (bytes) ----
#define WS_WEX   0          // 512*2 f64   : W_embed @ Wx
#define WS_PEX   8192       // 4096*2 f64  : (b_embed + pe[t]) @ Wx
#define WS_VWV   73728      // 2*8*2 f64   : v_i @ Wv
#define WS_LENS  76048      // 8 i32
#define WS_WT    76096      // 512*512 u16 : bf16 W_embed transposed [n][k]
#define WS_MASK  731456     // 32768 i32   : mask (k_dot) -> order (k_scan, in-place)
#define WS_ABF16 1310720    // 32768*512 u16 : bf16 data (kept rows only)

__device__ inline void threefry2x32(uint32_t k0, uint32_t k1, uint32_t x0, uint32_t x1,
                                    uint32_t& y0, uint32_t& y1) {
  uint32_t ks2 = k0 ^ k1 ^ 0x1BD11BDAu;
  x0 += k0; x1 += k1;
#define TFR(r) { x0 += x1; x1 = (x1 << (r)) | (x1 >> (32 - (r))); x1 ^= x0; }
  TFR(13) TFR(15) TFR(26) TFR(6)   x0 += k1;  x1 += ks2 + 1u;
  TFR(17) TFR(29) TFR(16) TFR(24)  x0 += ks2; x1 += k0 + 2u;
  TFR(13) TFR(15) TFR(26) TFR(6)   x0 += k0;  x1 += k1 + 3u;
  TFR(17) TFR(29) TFR(16) TFR(24)  x0 += k1;  x1 += ks2 + 4u;
  TFR(13) TFR(15) TFR(26) TFR(6)   x0 += ks2; x1 += k0 + 5u;
#undef TFR
  y0 = x0; y1 = x1;
}

__device__ inline uint32_t rb_bits(uint32_t k0, uint32_t k1, uint32_t idx) {
  uint32_t y0, y1;
  threefry2x32(k0, k1, 0u, idx, y0, y1);
  return y0 ^ y1;
}

__device__ inline double gumbel_from_bits(uint32_t bits) {
  uint32_t m = bits >> 9;
  float u = m ? (float)m * 1.1920928955078125e-07f : 1.17549435082228751e-38f;
  double lu = log((double)u);
  return -log(-lu);
}

__device__ inline uint16_t f2bf(float f) {
  union { float f; uint32_t u; } v; v.f = f;
  uint32_t u = v.u;
  return (uint16_t)((u + 0x7FFFu + ((u >> 16) & 1u)) >> 16);
}

__device__ inline double wredd(double v) {
#pragma unroll
  for (int o = 32; o > 0; o >>= 1) v += __shfl_xor(v, o, 64);
  return v;
}

// fast fp64 sincos for x in [0, ~4200): Cody-Waite + fdlibm polys, err ~1e-16
__device__ inline void fsincos(double x, double& sv, double& cv) {
  const double invpio2 = 6.36619772367581382433e-01;
  const double pio2_1  = 1.57079632673412561417e+00;
  const double pio2_1t = 6.07710050650619224932e-11;
  double fn = floor(x * invpio2 + 0.5);
  int n = (int)fn;
  double r = x - fn * pio2_1;
  r = r - fn * pio2_1t;
  double z = r * r;
  const double S1 = -1.66666666666666324348e-01, S2 = 8.33333333332248946124e-03,
               S3 = -1.98412698298579493134e-04, S4 = 2.75573137070700676789e-06,
               S5 = -2.50507602534068634195e-08, S6 = 1.58969099521155010221e-10;
  const double C1 = 4.16666666666666019037e-02, C2 = -1.38888888888741095749e-03,
               C3 = 2.48015872894767294178e-05, C4 = -2.75573143513906633035e-07,
               C5 = 2.08757232129817482790e-09, C6 = -1.13596475577881948265e-11;
  double ss = r + r * z * (S1 + z * (S2 + z * (S3 + z * (S4 + z * (S5 + z * S6)))));
  double cc = 1.0 + z * (-0.5 + z * (C1 + z * (C2 + z * (C3 + z * (C4 + z * (C5 + z * C6))))));
  int q = n & 3;
  sv = (q == 0) ? ss : (q == 1) ? cc : (q == 2) ? -ss : -cc;
  cv = (q == 0) ? cc : (q == 1) ? -ss : (q == 2) ? -cc : ss;
}

__device__ inline void gld_lds16(const void* g, void* l) {
  __builtin_amdgcn_global_load_lds(
      (const __attribute__((address_space(1))) void*)g,
      (__attribute__((address_space(3))) void*)l, 16, 0, 0);
}

// ---- k_prep: fp64 reduced operands + bf16 W^T (decision math UNCHANGED) ----
__global__ __launch_bounds__(64) void k_prep(
    const float* __restrict__ v0, const float* __restrict__ v1,
    const float* __restrict__ W, const float* __restrict__ be,
    const float* __restrict__ Wx, const float* __restrict__ Wv,
    char* __restrict__ ws) {
  double* Wex = (double*)(ws + WS_WEX);
  double* pex = (double*)(ws + WS_PEX);
  double* vWv = (double*)(ws + WS_VWV);
  uint16_t* Wt = (uint16_t*)(ws + WS_WT);
  __shared__ double divs[256];
  int blk = blockIdx.x;
  int lane = threadIdx.x;

  if (blk < 512) {
    int d = blk;
    double a0 = 0.0, a1 = 0.0;
    for (int it = 0; it < 8; ++it) {
      int h = it * 64 + lane;
      double w = (double)W[d * 512 + h];
      a0 += w * (double)Wx[2 * h];
      a1 += w * (double)Wx[2 * h + 1];
    }
    a0 = wredd(a0); a1 = wredd(a1);
    if (lane == 0) { Wex[2 * d] = a0; Wex[2 * d + 1] = a1; }
  } else if (blk < 4608) {
    const double c2 = -2.0 * 9.210340371976184 / 512.0;
    for (int it = 0; it < 4; ++it) {
      int f = it * 64 + lane;
      divs[f] = exp((double)f * c2);
    }
    __syncthreads();
    int t = blk - 512;
    double td = (double)t;
    double a0 = 0.0, a1 = 0.0;
    for (int it = 0; it < 8; ++it) {
      int h = it * 64 + lane;
      double dv = divs[h >> 1];
      double sv, cv;
      fsincos(td * dv, sv, cv);
      double pe = (h & 1) ? cv : sv;
      double pb = pe + (double)be[h];
      a0 += pb * (double)Wx[2 * h];
      a1 += pb * (double)Wx[2 * h + 1];
    }
    a0 = wredd(a0); a1 = wredd(a1);
    if (lane == 0) { pex[2 * t] = a0; pex[2 * t + 1] = a1; }
  } else if (blk < 4624) {
    int q = blk - 4608;
    int i = q >> 3, b = q & 7;
    const float* v = i ? v1 : v0;
    double a0 = 0.0, a1 = 0.0;
    for (int it = 0; it < 8; ++it) {
      int d = it * 64 + lane;
      double x = (double)v[b * 512 + d];
      a0 += x * (double)Wv[2 * d];
      a1 += x * (double)Wv[2 * d + 1];
    }
    a0 = wredd(a0); a1 = wredd(a1);
    if (lane == 0) { vWv[(i * 8 + b) * 2] = a0; vWv[(i * 8 + b) * 2 + 1] = a1; }
  } else {
    int kk = blk - 4624;
    for (int it = 0; it < 8; ++it) {
      int n = it * 64 + lane;
      Wt[(size_t)n * 512 + kk] = f2bf(W[kk * 512 + n]);
    }
  }
}

// ---- k_dot v4: coalesced transposed-lane dot; kept-rows-only bf16 store ----
__global__ __launch_bounds__(256) void k_dot(
    const float* __restrict__ data, const float* __restrict__ bfp,
    const char* __restrict__ wsc, int* __restrict__ mask,
    uint16_t* __restrict__ Abf) {
  const double* Wex = (const double*)(wsc + WS_WEX);
  const double* pex = (const double*)(wsc + WS_PEX);
  const double* vWv = (const double*)(wsc + WS_VWV);

  int wid = threadIdx.x >> 6;
  int lane = threadIdx.x & 63;
  int kbase = (blockIdx.x * 4 + wid) * 4;   // 4 tokens per wave

  // Wex slice in regs: lane l holds w{0,1}[u] = Wex[2*(u*64+l)+{0,1}]
  double w0[8], w1[8];
#pragma unroll
  for (int u = 0; u < 8; ++u) {
    double2 wv = *(const double2*)(Wex + 2 * (u * 64 + lane));
    w0[u] = wv.x; w1[u] = wv.y;
  }

  // 4 tokens' data held in regs across the decision (32 VGPR)
  float x[4][8];
  double d0s[4], d1s[4];
#pragma unroll
  for (int tt = 0; tt < 4; ++tt) {
    int k = kbase + tt;
    const float* dpt = data + (size_t)k * 512 + lane;
#pragma unroll
    for (int u = 0; u < 8; ++u) x[tt][u] = dpt[u * 64];   // coalesced dwords

    double d0 = 0.0, d1 = 0.0;
#pragma unroll
    for (int u = 0; u < 8; ++u) {
      double xd = (double)x[tt][u];
      d0 += xd * w0[u];
      d1 += xd * w1[u];
    }
    d0s[tt] = wredd(d0);
    d1s[tt] = wredd(d1);
  }

  // batched decision: lanes 0-15, lane = 4*tt + 2*i + j
  int dec = 0;
  if (lane < 16) {
    int tt = lane >> 2, i = (lane >> 1) & 1, j = lane & 1;
    double da = (tt & 2) ? ((tt & 1) ? d0s[3] : d0s[2])
                         : ((tt & 1) ? d0s[1] : d0s[0]);
    double db = (tt & 2) ? ((tt & 1) ? d1s[3] : d1s[2])
                         : ((tt & 1) ? d1s[1] : d1s[0]);
    double dj = j ? db : da;
    int kk = kbase + tt;
    int bb = kk >> 12, ttok = kk & 4095;
    uint32_t key0, key1;
    threefry2x32(0u, 42u, 0u, (uint32_t)i, key0, key1);
    double lj = 8.0 * (dj + pex[ttok * 2 + j]) + (double)bfp[j];
    double z = lj + vWv[(i * 8 + bb) * 2 + j]
                 + gumbel_from_bits(rb_bits(key0, key1, (uint32_t)(2 * kk + j)));
    double zo = __shfl_xor(z, 1, 64);
    dec = (z >= zo) ? 1 : 0;  // meaningful at j==0 lanes (class-0 wins ties)
  }
  unsigned long long bal = __ballot(dec);
  if (lane < 4)
    mask[kbase + lane] =
        (int)((bal >> (lane * 4)) & (bal >> (lane * 4 + 2)) & 1ULL);

  // bf16 store for KEPT tokens only (bal is wave-uniform -> uniform branches)
#pragma unroll
  for (int tt = 0; tt < 4; ++tt) {
    int keep = (int)((bal >> (tt * 4)) & (bal >> (tt * 4 + 2)) & 1ULL);
    if (keep) {
      uint16_t* ap = Abf + (size_t)(kbase + tt) * 512 + lane;
#pragma unroll
      for (int u = 0; u < 8; ++u) ap[u * 64] = f2bf(x[tt][u]);
    }
  }
}

// ---- k_scan: mask -> order (packed pos -> token, in-place over mask) + lens ----
__global__ __launch_bounds__(1024) void k_scan(
    int* __restrict__ morder, int* __restrict__ lens) {
  __shared__ int wsum[16];
  int b = blockIdx.x, tid = threadIdx.x;
  int wid = tid >> 6, lane = tid & 63;
  int t0 = tid * 4;
  int4 mv = *(const int4*)(morder + b * 4096 + t0);
  int m[4] = {mv.x, mv.y, mv.z, mv.w};
  int p = m[0] + m[1] + m[2] + m[3];

  int s = p;
#pragma unroll
  for (int off = 1; off < 64; off <<= 1) {
    int v = __shfl_up(s, off, 64);
    if (lane >= off) s += v;
  }
  if (lane == 63) wsum[wid] = s;
  __syncthreads();
  if (wid == 0) {
    int w = (lane < 16) ? wsum[lane] : 0;
#pragma unroll
    for (int off = 1; off < 16; off <<= 1) {
      int v = __shfl_up(w, off, 64);
      if (lane >= off) w += v;
    }
    if (lane < 16) wsum[lane] = w;
  }
  __syncthreads();
  int run = ((wid > 0) ? wsum[wid - 1] : 0) + s - p;
  int base = b * 4096;
  if (m[0]) morder[base + run] = t0 + 0;
  run += m[0];
  if (m[1]) morder[base + run] = t0 + 1;
  run += m[1];
  if (m[2]) morder[base + run] = t0 + 2;
  run += m[2];
  if (m[3]) morder[base + run] = t0 + 3;
  if (tid == 1023) lens[b] = wsum[15];
}

// ---- k_zero: fill out rows j >= lens[b] with zeros ----
__global__ __launch_bounds__(256) void k_zero(
    const char* __restrict__ wsc, float* __restrict__ out) {
  const int* lens = (const int*)(wsc + WS_LENS);
  int b = blockIdx.y;
  int j = blockIdx.x * 4 + (threadIdx.x >> 6);
  if (j < lens[b]) return;
  int lane = threadIdx.x & 63;
  float4 z = {0.f, 0.f, 0.f, 0.f};
  float* op = out + ((size_t)(b * 4096 + j)) * 512 + lane * 8;
  *(float4*)op = z;
  *(float4*)(op + 4) = z;
}

// ---- k_gemm v9: BM=64 for ~4 blocks/CU wave-overlap; packed-GLOBAL rows ----
#define BM 64
#define BN 128
#define BK 32

__global__ __launch_bounds__(256) void k_gemm(
    const uint16_t* __restrict__ Abf, const float* __restrict__ be,
    const char* __restrict__ wsc, float* __restrict__ out) {
  const uint16_t* Wt = (const uint16_t*)(wsc + WS_WT);
  const int* order = (const int*)(wsc + WS_MASK);
  const int* lens = (const int*)(wsc + WS_LENS);

  // prefix over batches (uniform -> scalar regs)
  int cum[9];
  cum[0] = 0;
#pragma unroll
  for (int i = 0; i < 8; ++i) cum[i + 1] = cum[i] + lens[i];
  int S = cum[8];

  int bid = blockIdx.x;
  int nb = bid & 3;               // N-block (128 cols each)
  int G = (bid >> 2) * BM;        // packed-GLOBAL row base
  if (G >= S) return;             // contiguous working ids 0..~ceil(S/64)*4

  int tid = threadIdx.x;
  int wave = tid >> 6, lane = tid & 63;
  int wm = wave & 1, wn = wave >> 1;     // 2x2 wave layout: 32-row x 64-col
  int quad = lane >> 4, l15 = lane & 15;
  int srow = lane >> 2;
  int scol = (lane & 3) * 8;

  __shared__ __align__(16) uint16_t As[BM * BK];   // 4 KB
  __shared__ __align__(16) uint16_t Bs[BN * BK];   // 8 KB

  f32x4 acc[2][4] = {};

  // per-lane gathered A row: resolve packed-global -> (batch, in-batch pos)
  int lr = wave * 16 + srow;      // local row in [0,64)
  int pg0 = G + lr;
  int b0 = 0, pin0 = pg0;
#pragma unroll
  for (int i = 1; i < 8; ++i)
    if (pg0 >= cum[i]) { b0 = i; pin0 = pg0 - cum[i]; }
  if (pg0 >= S) { b0 = 0; pin0 = 0; }  // clamp: reads a valid kept row
  int t0r = order[(b0 << 12) + pin0];
  const uint16_t* a0p = Abf + (((size_t)(b0 << 12) + t0r) << 9) + scol;
  const uint16_t* gB = Wt + (size_t)(nb * BN) * 512;
  const uint16_t* b0p = gB + (size_t)lr * 512 + scol;
  const uint16_t* b1p = b0p + (size_t)64 * 512;

  uint16_t* lA = As + (size_t)(wave * 16) * BK;  // wave-uniform LDS base
  uint16_t* lB = Bs + (size_t)(wave * 16) * BK;

  for (int k0 = 0; k0 < 512; k0 += BK) {
    gld_lds16(a0p + k0, lA);
    gld_lds16(b0p + k0, lB);
    gld_lds16(b1p + k0, lB + 64 * BK);
    __syncthreads();

    short8 af[2], bfr[4];
#pragma unroll
    for (int mi = 0; mi < 2; ++mi)
      af[mi] = *(const short8*)&As[(wm * 32 + mi * 16 + l15) * BK + quad * 8];
#pragma unroll
    for (int ni = 0; ni < 4; ++ni)
      bfr[ni] = *(const short8*)&Bs[(wn * 64 + ni * 16 + l15) * BK + quad * 8];
#pragma unroll
    for (int mi = 0; mi < 2; ++mi)
#pragma unroll
      for (int ni = 0; ni < 4; ++ni)
        acc[mi][ni] = __builtin_amdgcn_mfma_f32_16x16x32_bf16(af[mi], bfr[ni], acc[mi][ni], 0, 0, 0);
    __syncthreads();
  }

  // per-row (token, out-row) into LDS (As/Bs dead after final barrier)
  int* ords = (int*)As;
  int* orows = (int*)Bs;
  if (tid < 64) {
    int pg = G + tid;
    int bb = 0, pp = pg;
#pragma unroll
    for (int i = 1; i < 8; ++i)
      if (pg >= cum[i]) { bb = i; pp = pg - cum[i]; }
    bool val = pg < S;
    ords[tid] = val ? order[(bb << 12) + pp] : 0;
    orows[tid] = val ? ((bb << 12) + pp) : -1;
  }
  __syncthreads();

  // contiguous epilogue: out[orow][n] = 8*(acc + be + pe(t,n))
  const float c1 = -0.01798894603951557739f;  // -ln(10000)/512
#pragma unroll
  for (int ni = 0; ni < 4; ++ni) {
    int n = nb * BN + wn * 64 + ni * 16 + l15;
    float dv = __expf((float)(n & ~1) * c1);
    float ben = be[n];
#pragma unroll
    for (int mi = 0; mi < 2; ++mi) {
#pragma unroll
      for (int r = 0; r < 4; ++r) {
        int lrow = wm * 32 + mi * 16 + quad * 4 + r;
        int oj = orows[lrow];
        if (oj >= 0) {
          int t = ords[lrow];
          float ph = (float)t * dv;
          float pe = (n & 1) ? __cosf(ph) : __sinf(ph);
          out[((size_t)oj) * 512 + n] = 8.0f * (acc[mi][ni][r] + ben + pe);
        }
      }
    }
  }
}

extern "C" void kernel_launch(void* const* d_in, const int* in_sizes, int n_in,
                              void* d_out, int out_size, void* d_ws, size_t ws_size,
                              hipStream_t stream) {
  const float* data = (const float*)d_in[0];
  const float* v0   = (const float*)d_in[1];
  const float* v1   = (const float*)d_in[2];
  const float* W    = (const float*)d_in[3];
  const float* be   = (const float*)d_in[4];
  const float* Wx   = (const float*)d_in[5];
  const float* Wv   = (const float*)d_in[6];
  const float* bfp  = (const float*)d_in[7];
  char* ws = (char*)d_ws;
  float* out = (float*)d_out;
  uint16_t* Abf = (uint16_t*)(ws + WS_ABF16);

  hipLaunchKernelGGL(k_prep, dim3(5136), dim3(64), 0, stream, v0, v1, W, be, Wx, Wv, ws);
  hipLaunchKernelGGL(k_dot, dim3(2048), dim3(256), 0, stream,
                     data, bfp, (const char*)ws, (int*)(ws + WS_MASK), Abf);
  hipLaunchKernelGGL(k_scan, dim3(8), dim3(1024), 0, stream,
                     (int*)(ws + WS_MASK), (int*)(ws + WS_LENS));
  hipLaunchKernelGGL(k_zero, dim3(1024, 8), dim3(256), 0, stream, (const char*)ws, out);
  hipLaunchKernelGGL(k_gemm, dim3(2048), dim3(256), 0, stream,
                     Abf, be, (const char*)ws, out);
}

// Round 9
// 157.823 us; speedup vs baseline: 1.1922x; 1.0446x over previous
//
#include <hip/hip_runtime.h>
#include <stdint.h>

// PRNG layout: partitionable counter-mode, bits = y0 ^ y1 (verified round 1)
// Round 9 (resubmit of round 8 — GPUAcquisitionTimeout, kernel never ran;
// precedent: rounds 2->3 and 5->6 infra failures, identical resubmits passed).
// (a) fuse k_zero into k_gemm — grid 2048 has ~1064 idle blocks
// (bid >= 4*ceil(S/64)); they now write the complementary zero rows
// (j >= lens[b]), deleting one serialized ~9us dispatch and overlapping the
// 34MB of zero-stores under GEMM compute. (b) k_dot: lane owns 4 consecutive
// elements (h = u*256 + lane*4 + q) -> 2 dwordx4 loads + 2 short4 stores per
// token instead of 8 dwords + 8 strided u16 stores (4x fewer mem instrs,
// same bytes/coalescing; fp64 regroup ~1e-16, decision margins O(1)).

#define NB 8
#define NT 4096
#define ND 512
#define NH 512
#define NTOK (NB * NT)

typedef __attribute__((ext_vector_type(8))) short short8;
typedef __attribute__((ext_vector_type(4))) short short4v;
typedef __attribute__((ext_vector_type(4))) float f32x4;

// ---- workspace layout (bytes) ----
#define WS_WEX   0          // 512*2 f64   : W_embed @ Wx
#define WS_PEX   8192       // 4096*2 f64  : (b_embed + pe[t]) @ Wx
#define WS_VWV   73728      // 2*8*2 f64   : v_i @ Wv
#define WS_LENS  76048      // 8 i32
#define WS_WT    76096      // 512*512 u16 : bf16 W_embed transposed [n][k]
#define WS_MASK  731456     // 32768 i32   : mask (k_dot) -> order (k_scan, in-place)
#define WS_ABF16 1310720    // 32768*512 u16 : bf16 data (kept rows only)

__device__ inline void threefry2x32(uint32_t k0, uint32_t k1, uint32_t x0, uint32_t x1,
                                    uint32_t& y0, uint32_t& y1) {
  uint32_t ks2 = k0 ^ k1 ^ 0x1BD11BDAu;
  x0 += k0; x1 += k1;
#define TFR(r) { x0 += x1; x1 = (x1 << (r)) | (x1 >> (32 - (r))); x1 ^= x0; }
  TFR(13) TFR(15) TFR(26) TFR(6)   x0 += k1;  x1 += ks2 + 1u;
  TFR(17) TFR(29) TFR(16) TFR(24)  x0 += ks2; x1 += k0 + 2u;
  TFR(13) TFR(15) TFR(26) TFR(6)   x0 += k0;  x1 += k1 + 3u;
  TFR(17) TFR(29) TFR(16) TFR(24)  x0 += k1;  x1 += ks2 + 4u;
  TFR(13) TFR(15) TFR(26) TFR(6)   x0 += ks2; x1 += k0 + 5u;
#undef TFR
  y0 = x0; y1 = x1;
}

__device__ inline uint32_t rb_bits(uint32_t k0, uint32_t k1, uint32_t idx) {
  uint32_t y0, y1;
  threefry2x32(k0, k1, 0u, idx, y0, y1);
  return y0 ^ y1;
}

__device__ inline double gumbel_from_bits(uint32_t bits) {
  uint32_t m = bits >> 9;
  float u = m ? (float)m * 1.1920928955078125e-07f : 1.17549435082228751e-38f;
  double lu = log((double)u);
  return -log(-lu);
}

__device__ inline uint16_t f2bf(float f) {
  union { float f; uint32_t u; } v; v.f = f;
  uint32_t u = v.u;
  return (uint16_t)((u + 0x7FFFu + ((u >> 16) & 1u)) >> 16);
}

__device__ inline double wredd(double v) {
#pragma unroll
  for (int o = 32; o > 0; o >>= 1) v += __shfl_xor(v, o, 64);
  return v;
}

// fast fp64 sincos for x in [0, ~4200): Cody-Waite + fdlibm polys, err ~1e-16
__device__ inline void fsincos(double x, double& sv, double& cv) {
  const double invpio2 = 6.36619772367581382433e-01;
  const double pio2_1  = 1.57079632673412561417e+00;
  const double pio2_1t = 6.07710050650619224932e-11;
  double fn = floor(x * invpio2 + 0.5);
  int n = (int)fn;
  double r = x - fn * pio2_1;
  r = r - fn * pio2_1t;
  double z = r * r;
  const double S1 = -1.66666666666666324348e-01, S2 = 8.33333333332248946124e-03,
               S3 = -1.98412698298579493134e-04, S4 = 2.75573137070700676789e-06,
               S5 = -2.50507602534068634195e-08, S6 = 1.58969099521155010221e-10;
  const double C1 = 4.16666666666666019037e-02, C2 = -1.38888888888741095749e-03,
               C3 = 2.48015872894767294178e-05, C4 = -2.75573143513906633035e-07,
               C5 = 2.08757232129817482790e-09, C6 = -1.13596475577881948265e-11;
  double ss = r + r * z * (S1 + z * (S2 + z * (S3 + z * (S4 + z * (S5 + z * S6)))));
  double cc = 1.0 + z * (-0.5 + z * (C1 + z * (C2 + z * (C3 + z * (C4 + z * (C5 + z * C6))))));
  int q = n & 3;
  sv = (q == 0) ? ss : (q == 1) ? cc : (q == 2) ? -ss : -cc;
  cv = (q == 0) ? cc : (q == 1) ? -ss : (q == 2) ? -cc : ss;
}

__device__ inline void gld_lds16(const void* g, void* l) {
  __builtin_amdgcn_global_load_lds(
      (const __attribute__((address_space(1))) void*)g,
      (__attribute__((address_space(3))) void*)l, 16, 0, 0);
}

// ---- k_prep: fp64 reduced operands + bf16 W^T (decision math UNCHANGED) ----
__global__ __launch_bounds__(64) void k_prep(
    const float* __restrict__ v0, const float* __restrict__ v1,
    const float* __restrict__ W, const float* __restrict__ be,
    const float* __restrict__ Wx, const float* __restrict__ Wv,
    char* __restrict__ ws) {
  double* Wex = (double*)(ws + WS_WEX);
  double* pex = (double*)(ws + WS_PEX);
  double* vWv = (double*)(ws + WS_VWV);
  uint16_t* Wt = (uint16_t*)(ws + WS_WT);
  __shared__ double divs[256];
  int blk = blockIdx.x;
  int lane = threadIdx.x;

  if (blk < 512) {
    int d = blk;
    double a0 = 0.0, a1 = 0.0;
    for (int it = 0; it < 8; ++it) {
      int h = it * 64 + lane;
      double w = (double)W[d * 512 + h];
      a0 += w * (double)Wx[2 * h];
      a1 += w * (double)Wx[2 * h + 1];
    }
    a0 = wredd(a0); a1 = wredd(a1);
    if (lane == 0) { Wex[2 * d] = a0; Wex[2 * d + 1] = a1; }
  } else if (blk < 4608) {
    const double c2 = -2.0 * 9.210340371976184 / 512.0;
    for (int it = 0; it < 4; ++it) {
      int f = it * 64 + lane;
      divs[f] = exp((double)f * c2);
    }
    __syncthreads();
    int t = blk - 512;
    double td = (double)t;
    double a0 = 0.0, a1 = 0.0;
    for (int it = 0; it < 8; ++it) {
      int h = it * 64 + lane;
      double dv = divs[h >> 1];
      double sv, cv;
      fsincos(td * dv, sv, cv);
      double pe = (h & 1) ? cv : sv;
      double pb = pe + (double)be[h];
      a0 += pb * (double)Wx[2 * h];
      a1 += pb * (double)Wx[2 * h + 1];
    }
    a0 = wredd(a0); a1 = wredd(a1);
    if (lane == 0) { pex[2 * t] = a0; pex[2 * t + 1] = a1; }
  } else if (blk < 4624) {
    int q = blk - 4608;
    int i = q >> 3, b = q & 7;
    const float* v = i ? v1 : v0;
    double a0 = 0.0, a1 = 0.0;
    for (int it = 0; it < 8; ++it) {
      int d = it * 64 + lane;
      double x = (double)v[b * 512 + d];
      a0 += x * (double)Wv[2 * d];
      a1 += x * (double)Wv[2 * d + 1];
    }
    a0 = wredd(a0); a1 = wredd(a1);
    if (lane == 0) { vWv[(i * 8 + b) * 2] = a0; vWv[(i * 8 + b) * 2 + 1] = a1; }
  } else {
    int kk = blk - 4624;
    for (int it = 0; it < 8; ++it) {
      int n = it * 64 + lane;
      Wt[(size_t)n * 512 + kk] = f2bf(W[kk * 512 + n]);
    }
  }
}

// ---- k_dot v5: dwordx4 loads (lane owns 4 consecutive h); kept-only store ----
__global__ __launch_bounds__(256) void k_dot(
    const float* __restrict__ data, const float* __restrict__ bfp,
    const char* __restrict__ wsc, int* __restrict__ mask,
    uint16_t* __restrict__ Abf) {
  const double* Wex = (const double*)(wsc + WS_WEX);
  const double* pex = (const double*)(wsc + WS_PEX);
  const double* vWv = (const double*)(wsc + WS_VWV);

  int wid = threadIdx.x >> 6;
  int lane = threadIdx.x & 63;
  int kbase = (blockIdx.x * 4 + wid) * 4;   // 4 tokens per wave

  // lane l owns h = (e>>2)*256 + l*4 + (e&3), e = 0..7
  double w0[8], w1[8];
#pragma unroll
  for (int e = 0; e < 8; ++e) {
    int h = (e >> 2) * 256 + lane * 4 + (e & 3);
    double2 wv = *(const double2*)(Wex + 2 * h);
    w0[e] = wv.x; w1[e] = wv.y;
  }

  // 4 tokens' data held in regs across the decision (32 VGPR)
  float x[4][8];
  double d0s[4], d1s[4];
#pragma unroll
  for (int tt = 0; tt < 4; ++tt) {
    int k = kbase + tt;
    const float4* dpt = (const float4*)(data + (size_t)k * 512 + lane * 4);
    float4 xa = dpt[0];        // h = lane*4 + 0..3
    float4 xb = dpt[64];       // h = 256 + lane*4 + 0..3
    x[tt][0] = xa.x; x[tt][1] = xa.y; x[tt][2] = xa.z; x[tt][3] = xa.w;
    x[tt][4] = xb.x; x[tt][5] = xb.y; x[tt][6] = xb.z; x[tt][7] = xb.w;

    double d0 = 0.0, d1 = 0.0;
#pragma unroll
    for (int e = 0; e < 8; ++e) {
      double xd = (double)x[tt][e];
      d0 += xd * w0[e];
      d1 += xd * w1[e];
    }
    d0s[tt] = wredd(d0);
    d1s[tt] = wredd(d1);
  }

  // batched decision: lanes 0-15, lane = 4*tt + 2*i + j
  int dec = 0;
  if (lane < 16) {
    int tt = lane >> 2, i = (lane >> 1) & 1, j = lane & 1;
    double da = (tt & 2) ? ((tt & 1) ? d0s[3] : d0s[2])
                         : ((tt & 1) ? d0s[1] : d0s[0]);
    double db = (tt & 2) ? ((tt & 1) ? d1s[3] : d1s[2])
                         : ((tt & 1) ? d1s[1] : d1s[0]);
    double dj = j ? db : da;
    int kk = kbase + tt;
    int bb = kk >> 12, ttok = kk & 4095;
    uint32_t key0, key1;
    threefry2x32(0u, 42u, 0u, (uint32_t)i, key0, key1);
    double lj = 8.0 * (dj + pex[ttok * 2 + j]) + (double)bfp[j];
    double z = lj + vWv[(i * 8 + bb) * 2 + j]
                 + gumbel_from_bits(rb_bits(key0, key1, (uint32_t)(2 * kk + j)));
    double zo = __shfl_xor(z, 1, 64);
    dec = (z >= zo) ? 1 : 0;  // meaningful at j==0 lanes (class-0 wins ties)
  }
  unsigned long long bal = __ballot(dec);
  if (lane < 4)
    mask[kbase + lane] =
        (int)((bal >> (lane * 4)) & (bal >> (lane * 4 + 2)) & 1ULL);

  // bf16 store for KEPT tokens only (bal wave-uniform -> uniform branches)
#pragma unroll
  for (int tt = 0; tt < 4; ++tt) {
    int keep = (int)((bal >> (tt * 4)) & (bal >> (tt * 4 + 2)) & 1ULL);
    if (keep) {
      uint16_t* ap = Abf + (size_t)(kbase + tt) * 512 + lane * 4;
      short4v s0, s1;
#pragma unroll
      for (int q = 0; q < 4; ++q) {
        s0[q] = (short)f2bf(x[tt][q]);
        s1[q] = (short)f2bf(x[tt][4 + q]);
      }
      *(short4v*)ap = s0;
      *(short4v*)(ap + 256) = s1;
    }
  }
}

// ---- k_scan: mask -> order (packed pos -> token, in-place over mask) + lens ----
__global__ __launch_bounds__(1024) void k_scan(
    int* __restrict__ morder, int* __restrict__ lens) {
  __shared__ int wsum[16];
  int b = blockIdx.x, tid = threadIdx.x;
  int wid = tid >> 6, lane = tid & 63;
  int t0 = tid * 4;
  int4 mv = *(const int4*)(morder + b * 4096 + t0);
  int m[4] = {mv.x, mv.y, mv.z, mv.w};
  int p = m[0] + m[1] + m[2] + m[3];

  int s = p;
#pragma unroll
  for (int off = 1; off < 64; off <<= 1) {
    int v = __shfl_up(s, off, 64);
    if (lane >= off) s += v;
  }
  if (lane == 63) wsum[wid] = s;
  __syncthreads();
  if (wid == 0) {
    int w = (lane < 16) ? wsum[lane] : 0;
#pragma unroll
    for (int off = 1; off < 16; off <<= 1) {
      int v = __shfl_up(w, off, 64);
      if (lane >= off) w += v;
    }
    if (lane < 16) wsum[lane] = w;
  }
  __syncthreads();
  int run = ((wid > 0) ? wsum[wid - 1] : 0) + s - p;
  int base = b * 4096;
  if (m[0]) morder[base + run] = t0 + 0;
  run += m[0];
  if (m[1]) morder[base + run] = t0 + 1;
  run += m[1];
  if (m[2]) morder[base + run] = t0 + 2;
  run += m[2];
  if (m[3]) morder[base + run] = t0 + 3;
  if (tid == 1023) lens[b] = wsum[15];
}

// ---- k_gemm v10: GEMM blocks + idle blocks zero-fill (k_zero fused) ----
#define BM 64
#define BN 128
#define BK 32

__global__ __launch_bounds__(256) void k_gemm(
    const uint16_t* __restrict__ Abf, const float* __restrict__ be,
    const char* __restrict__ wsc, float* __restrict__ out) {
  const uint16_t* Wt = (const uint16_t*)(wsc + WS_WT);
  const int* order = (const int*)(wsc + WS_MASK);
  const int* lens = (const int*)(wsc + WS_LENS);

  // prefix over batches (uniform -> scalar regs)
  int cum[9];
  cum[0] = 0;
#pragma unroll
  for (int i = 0; i < 8; ++i) cum[i + 1] = cum[i] + lens[i];
  int S = cum[8];

  int bid = blockIdx.x;
  int tid = threadIdx.x;
  int nWB = (S + BM - 1) / BM;    // working row-blocks

  if (bid >= nWB * 4) {
    // ---- zero-fill role: rows (b, j>=lens[b]), complementary to GEMM ----
    int vid = bid - nWB * 4;
    int V = (int)gridDim.x - nWB * 4;   // >0 here (bid >= nWB*4 implies V>0)
    int zcum[9];
    zcum[0] = 0;
#pragma unroll
    for (int i = 0; i < 8; ++i) zcum[i + 1] = zcum[i] + (4096 - lens[i]);
    int Z = zcum[8];
    int wv = tid >> 6, lane = tid & 63;
    float4 zz = {0.f, 0.f, 0.f, 0.f};
    for (int z = vid * 4 + wv; z < Z; z += V * 4) {
      int bb = 0, off = z;
#pragma unroll
      for (int i = 1; i < 8; ++i)
        if (z >= zcum[i]) { bb = i; off = z - zcum[i]; }
      int j = lens[bb] + off;
      float* op = out + ((size_t)(bb * 4096 + j)) * 512 + lane * 8;
      *(float4*)op = zz;
      *(float4*)(op + 4) = zz;
    }
    return;
  }

  int nb = bid & 3;               // N-block (128 cols each)
  int G = (bid >> 2) * BM;        // packed-GLOBAL row base

  int wave = tid >> 6, lane = tid & 63;
  int wm = wave & 1, wn = wave >> 1;     // 2x2 wave layout: 32-row x 64-col
  int quad = lane >> 4, l15 = lane & 15;
  int srow = lane >> 2;
  int scol = (lane & 3) * 8;

  __shared__ __align__(16) uint16_t As[BM * BK];   // 4 KB
  __shared__ __align__(16) uint16_t Bs[BN * BK];   // 8 KB

  f32x4 acc[2][4] = {};

  // per-lane gathered A row: resolve packed-global -> (batch, in-batch pos)
  int lr = wave * 16 + srow;      // local row in [0,64)
  int pg0 = G + lr;
  int b0 = 0, pin0 = pg0;
#pragma unroll
  for (int i = 1; i < 8; ++i)
    if (pg0 >= cum[i]) { b0 = i; pin0 = pg0 - cum[i]; }
  if (pg0 >= S) { b0 = 0; pin0 = 0; }  // clamp: reads a valid kept row
  int t0r = order[(b0 << 12) + pin0];
  const uint16_t* a0p = Abf + (((size_t)(b0 << 12) + t0r) << 9) + scol;
  const uint16_t* gB = Wt + (size_t)(nb * BN) * 512;
  const uint16_t* b0p = gB + (size_t)lr * 512 + scol;
  const uint16_t* b1p = b0p + (size_t)64 * 512;

  uint16_t* lA = As + (size_t)(wave * 16) * BK;  // wave-uniform LDS base
  uint16_t* lB = Bs + (size_t)(wave * 16) * BK;

  for (int k0 = 0; k0 < 512; k0 += BK) {
    gld_lds16(a0p + k0, lA);
    gld_lds16(b0p + k0, lB);
    gld_lds16(b1p + k0, lB + 64 * BK);
    __syncthreads();

    short8 af[2], bfr[4];
#pragma unroll
    for (int mi = 0; mi < 2; ++mi)
      af[mi] = *(const short8*)&As[(wm * 32 + mi * 16 + l15) * BK + quad * 8];
#pragma unroll
    for (int ni = 0; ni < 4; ++ni)
      bfr[ni] = *(const short8*)&Bs[(wn * 64 + ni * 16 + l15) * BK + quad * 8];
#pragma unroll
    for (int mi = 0; mi < 2; ++mi)
#pragma unroll
      for (int ni = 0; ni < 4; ++ni)
        acc[mi][ni] = __builtin_amdgcn_mfma_f32_16x16x32_bf16(af[mi], bfr[ni], acc[mi][ni], 0, 0, 0);
    __syncthreads();
  }

  // per-row (token, out-row) into LDS (As/Bs dead after final barrier)
  int* ords = (int*)As;
  int* orows = (int*)Bs;
  if (tid < 64) {
    int pg = G + tid;
    int bb = 0, pp = pg;
#pragma unroll
    for (int i = 1; i < 8; ++i)
      if (pg >= cum[i]) { bb = i; pp = pg - cum[i]; }
    bool val = pg < S;
    ords[tid] = val ? order[(bb << 12) + pp] : 0;
    orows[tid] = val ? ((bb << 12) + pp) : -1;
  }
  __syncthreads();

  // contiguous epilogue: out[orow][n] = 8*(acc + be + pe(t,n))
  const float c1 = -0.01798894603951557739f;  // -ln(10000)/512
#pragma unroll
  for (int ni = 0; ni < 4; ++ni) {
    int n = nb * BN + wn * 64 + ni * 16 + l15;
    float dv = __expf((float)(n & ~1) * c1);
    float ben = be[n];
#pragma unroll
    for (int mi = 0; mi < 2; ++mi) {
#pragma unroll
      for (int r = 0; r < 4; ++r) {
        int lrow = wm * 32 + mi * 16 + quad * 4 + r;
        int oj = orows[lrow];
        if (oj >= 0) {
          int t = ords[lrow];
          float ph = (float)t * dv;
          float pe = (n & 1) ? __cosf(ph) : __sinf(ph);
          out[((size_t)oj) * 512 + n] = 8.0f * (acc[mi][ni][r] + ben + pe);
        }
      }
    }
  }
}

extern "C" void kernel_launch(void* const* d_in, const int* in_sizes, int n_in,
                              void* d_out, int out_size, void* d_ws, size_t ws_size,
                              hipStream_t stream) {
  const float* data = (const float*)d_in[0];
  const float* v0   = (const float*)d_in[1];
  const float* v1   = (const float*)d_in[2];
  const float* W    = (const float*)d_in[3];
  const float* be   = (const float*)d_in[4];
  const float* Wx   = (const float*)d_in[5];
  const float* Wv   = (const float*)d_in[6];
  const float* bfp  = (const float*)d_in[7];
  char* ws = (char*)d_ws;
  float* out = (float*)d_out;
  uint16_t* Abf = (uint16_t*)(ws + WS_ABF16);

  hipLaunchKernelGGL(k_prep, dim3(5136), dim3(64), 0, stream, v0, v1, W, be, Wx, Wv, ws);
  hipLaunchKernelGGL(k_dot, dim3(2048), dim3(256), 0, stream,
                     data, bfp, (const char*)ws, (int*)(ws + WS_MASK), Abf);
  hipLaunchKernelGGL(k_scan, dim3(8), dim3(1024), 0, stream,
                     (int*)(ws + WS_MASK), (int*)(ws + WS_LENS));
  hipLaunchKernelGGL(k_gemm, dim3(2048), dim3(256), 0, stream,
                     Abf, be, (const char*)ws, out);
}